// Round 2
// baseline (1365.086 us; speedup 1.0000x reference)
//
#include <hip/hip_runtime.h>

// Problem constants (from setup_inputs): N=32768 pts, C=256 clusters, P=128,
// E=1024 edges, grid 32^3. Channels 1->16->32->64, three stride-2 SAME convs.
#define PPC 128

// Fractional box-overlap of [v, v+gs] with cell [i/32, (i+1)/32], divided by gs.
__device__ __forceinline__ float ovlap(float v, float gs, float inv_gs, int i) {
  const float ns = 0.03125f;                 // 1/32, exact
  float lo = (float)i * ns;                  // exact (multiple of 2^-5)
  float o  = fminf(v + gs, lo + ns) - fmaxf(v, lo);
  return fmaxf(o, 0.0f) * inv_gs;
}

// ---------------------------------------------------------------------------
// Kernel 1: per-cluster voxelize (in LDS) + conv1 (preact, no bias/relu)
//   y1[c][oc(16)][z16][y16][x16]  (fp32, 64 MB in d_ws)
// One block (256 thr) per cluster. LDS: 128KB vox + 3KB reduce.
// ---------------------------------------------------------------------------
__global__ __launch_bounds__(256) void k_vox_conv1(
    const float* __restrict__ data,           // [32768,5]
    const int*   __restrict__ clusts,         // [C,128]
    const unsigned char* __restrict__ maskb,  // [C,128] bool bytes (or int32 - detected)
    const float* __restrict__ W1,             // [16,27]
    float* __restrict__ y1)                   // [C,16,4096]
{
  __shared__ float vox[32768];
  __shared__ float rmn[PPC * 3];
  __shared__ float rmx[PPC * 3];
  const int c = blockIdx.x;
  const int t = threadIdx.x;

  for (int i = t; i < 32768; i += 256) vox[i] = 0.f;

  // mask dtype sniff: all-true mask => bool bytes give maskb[1]==1, int32 gives 0
  const bool m32 = (maskb[1] == 0);

  if (t < PPC) {
    int idx = clusts[c * PPC + t];
    const float* dp = data + idx * 5;
    bool m = m32 ? (((const int*)maskb)[c * PPC + t] != 0)
                 : (maskb[c * PPC + t] != 0);
#pragma unroll
    for (int d = 0; d < 3; ++d) {
      float p = dp[d];
      rmn[t * 3 + d] = m ? p : 1e9f;
      rmx[t * 3 + d] = m ? p : -1e9f;
    }
  }
  __syncthreads();
  for (int off = 64; off >= 1; off >>= 1) {
    if (t < off) {
#pragma unroll
      for (int d = 0; d < 3; ++d) {
        rmn[t * 3 + d] = fminf(rmn[t * 3 + d], rmn[(t + off) * 3 + d]);
        rmx[t * 3 + d] = fmaxf(rmx[t * 3 + d], rmx[(t + off) * 3 + d]);
      }
    }
    __syncthreads();
  }
  const float mn0 = rmn[0], mn1 = rmn[1], mn2 = rmn[2];
  const float rg0 = rmx[0] - mn0, rg1 = rmx[1] - mn1, rg2 = rmx[2] - mn2;
  const float mr = fmaxf(rg0, fmaxf(rg1, rg2)) + 1.0f;
  const float gs = 1.0f / mr;
  const float inv_gs = 1.0f / gs;

  // ---- scatter: 2 threads per point, split outer-i by parity ----
  {
    const int p = t >> 1, h = t & 1;
    int idx = clusts[c * PPC + p];
    const float* dp = data + idx * 5;
    bool m = m32 ? (((const int*)maskb)[c * PPC + p] != 0)
                 : (maskb[c * PPC + p] != 0);
    float w = m ? dp[4] : 0.f;
    if (w != 0.f) {
      float v0 = (dp[0] - mn0 - rg0 * 0.5f - 0.5f) * gs + 0.5f;
      float v1 = (dp[1] - mn1 - rg1 * 0.5f - 0.5f) * gs + 0.5f;
      float v2 = (dp[2] - mn2 - rg2 * 0.5f - 0.5f) * gs + 0.5f;
      int i0 = max(0, (int)floorf(v0 * 32.f) - 1), i1 = min(31, (int)floorf((v0 + gs) * 32.f) + 1);
      int j0 = max(0, (int)floorf(v1 * 32.f) - 1), j1 = min(31, (int)floorf((v1 + gs) * 32.f) + 1);
      int k0 = max(0, (int)floorf(v2 * 32.f) - 1), k1 = min(31, (int)floorf((v2 + gs) * 32.f) + 1);
      for (int i = i0 + h; i <= i1; i += 2) {
        float oi = ovlap(v0, gs, inv_gs, i);
        if (oi <= 0.f) continue;
        float wi = w * oi;
        for (int j = j0; j <= j1; ++j) {
          float oj = ovlap(v1, gs, inv_gs, j);
          if (oj <= 0.f) continue;
          float wij = wi * oj;
          for (int k = k0; k <= k1; ++k) {
            float ok = ovlap(v2, gs, inv_gs, k);
            if (ok > 0.f) atomicAdd(&vox[(i << 10) + (j << 5) + k], wij * ok);
          }
        }
      }
    }
  }
  __syncthreads();

  // ---- conv1: 16 spatials/thread, 16 oc each. SAME pad: in = 2o+t, pad at 32 ----
  for (int si = 0; si < 16; ++si) {
    int s = t + (si << 8);                    // 0..4095, z = s>>8 (= si), y, x
    int oz = s >> 8, oy = (s >> 4) & 15, ox = s & 15;
    float xv[27];
#pragma unroll
    for (int td = 0; td < 3; ++td)
#pragma unroll
      for (int th = 0; th < 3; ++th)
#pragma unroll
        for (int tw = 0; tw < 3; ++tw) {
          int z = 2 * oz + td, y = 2 * oy + th, x = 2 * ox + tw;
          bool okb = (z < 32) & (y < 32) & (x < 32);
          xv[(td * 3 + th) * 3 + tw] = okb ? vox[(z << 10) + (y << 5) + x] : 0.f;
        }
#pragma unroll
    for (int oc = 0; oc < 16; ++oc) {
      float a = 0.f;
#pragma unroll
      for (int tp = 0; tp < 27; ++tp) a = fmaf(W1[oc * 27 + tp], xv[tp], a);
      y1[(((c << 4) + oc) << 12) + s] = a;    // preact: bias+relu applied in k_edge
    }
  }
}

// ---------------------------------------------------------------------------
// Kernel 2: per-edge fused conv2+conv3+pool+FC. One block (256 thr) per edge.
// x1 = relu(y1[ca]+y1[cb]+b1) staged 2ch at a time into LDS [2][17][17][17];
// conv2 accumulates 2 spatial x 32oc in regs; x2 -> LDS (padded z*85+y*10+x)
// in two 16-ch halves; conv3 16oc/wave; shfl pool; fused FC.
// ---------------------------------------------------------------------------
__global__ __launch_bounds__(256) void k_edge(
    const void*  __restrict__ eidx_raw,       // [2,E] int32 or int64 (detected)
    const float* __restrict__ y1,             // [C,16,4096]
    const float* __restrict__ b1,             // 16
    const float* __restrict__ W2,             // [32,16,27]
    const float* __restrict__ b2,             // 32
    const float* __restrict__ W3,             // [64,32,27]
    const float* __restrict__ b3,             // 64
    const float* __restrict__ Wfc,            // [64,64] (k-major)
    const float* __restrict__ bfc,            // 64
    float* __restrict__ out,                  // [E,64]
    int E)
{
  constexpr int ICS = 688;                    // padded x2 ch-stride (z*85+y*10+x, max 672)
  __shared__ float smem[16 * ICS];            // 43KB; also holds x1 stage (2*4913=9826)
  __shared__ float pooled[64];
  const int e = blockIdx.x;
  const int t = threadIdx.x;

  // edge_index dtype sniff (values < 256 -> int64 high words are 0)
  const int* e32 = (const int*)eidx_raw;
  const long long* e64 = (const long long*)eidx_raw;
  const bool is64 = (e32[1] == 0) & (e32[3] == 0) & (e32[5] == 0) & (e32[7] == 0);
  const int ca = is64 ? (int)e64[e] : e32[e];
  const int cb = is64 ? (int)e64[E + e] : e32[E + e];
  const float* Ap = y1 + (size_t)ca * 65536;
  const float* Bp = y1 + (size_t)cb * 65536;

  float acc2[2][32];
#pragma unroll
  for (int h = 0; h < 2; ++h)
#pragma unroll
    for (int o = 0; o < 32; ++o) acc2[h][o] = 0.f;

  const int oz0 = t >> 6, oy0 = (t >> 3) & 7, ox0 = t & 7;  // spatial s0=t, s1=t+256

  // ================= conv2 =================
  for (int icg = 0; icg < 8; ++icg) {
    __syncthreads();
    // stage 2 input channels: [icl][z17][y17][x17], coord 16 = SAME right-pad (zero)
#pragma unroll 4
    for (int i = t; i < 9826; i += 256) {
      int icl = i / 4913;
      int r = i - icl * 4913;
      int z = r / 289; r -= z * 289;
      int y = r / 17;
      int x = r - y * 17;
      float vv = 0.f;
      if ((z < 16) & (y < 16) & (x < 16)) {
        int ic = icg * 2 + icl;
        int gg = (ic << 12) + (z << 8) + (y << 4) + x;
        vv = fmaxf(Ap[gg] + Bp[gg] + b1[ic], 0.f);
      }
      smem[i] = vv;
    }
    __syncthreads();
#pragma unroll 1
    for (int icl = 0; icl < 2; ++icl) {
      const int ic = icg * 2 + icl;
      float xv0[27], xv1[27];
#pragma unroll
      for (int td = 0; td < 3; ++td)
#pragma unroll
        for (int th = 0; th < 3; ++th)
#pragma unroll
          for (int tw = 0; tw < 3; ++tw) {
            int zz = 2 * oz0 + td, yy = 2 * oy0 + th, xx = 2 * ox0 + tw;
            int base = icl * 4913 + zz * 289 + yy * 17 + xx;
            int tp = (td * 3 + th) * 3 + tw;
            xv0[tp] = smem[base];
            xv1[tp] = smem[base + 8 * 289];   // s1 = s0 + 4 in oz -> +8 in z
          }
      const float* wrow = W2 + ic * 27;       // + oc*432
#pragma unroll
      for (int oc = 0; oc < 32; ++oc) {
#pragma unroll
        for (int tp = 0; tp < 27; ++tp) {
          float w = wrow[oc * 432 + tp];      // uniform -> s_load
          acc2[0][oc] = fmaf(w, xv0[tp], acc2[0][oc]);
          acc2[1][oc] = fmaf(w, xv1[tp], acc2[1][oc]);
        }
      }
    }
  }

  // ================= conv3 (two 16-ch halves of x2) =================
  float acc3[16];
#pragma unroll
  for (int o = 0; o < 16; ++o) acc3[o] = 0.f;
  const int l = t & 63, wid = t >> 6;
  const int OZ = l >> 4, OY = (l >> 2) & 3, OX = l & 3;

#pragma unroll 1
  for (int half = 0; half < 2; ++half) {
    __syncthreads();
#pragma unroll
    for (int h = 0; h < 2; ++h) {
      int z = oz0 + (h << 2);
#pragma unroll
      for (int o = 0; o < 16; ++o) {
        int oc = (half << 4) + o;
        smem[o * ICS + z * 85 + oy0 * 10 + ox0] = fmaxf(acc2[h][oc] + b2[oc], 0.f);
      }
    }
    __syncthreads();
#pragma unroll 1
    for (int icl = 0; icl < 16; ++icl) {
      const int ic = (half << 4) + icl;
      float xv[27];
#pragma unroll
      for (int td = 0; td < 3; ++td)
#pragma unroll
        for (int th = 0; th < 3; ++th)
#pragma unroll
          for (int tw = 0; tw < 3; ++tw) {
            int zz = 2 * OZ + td, yy = 2 * OY + th, xx = 2 * OX + tw;
            bool okb = (zz < 8) & (yy < 8) & (xx < 8);  // coord 8 = SAME right-pad
            xv[(td * 3 + th) * 3 + tw] = okb ? smem[icl * ICS + zz * 85 + yy * 10 + xx] : 0.f;
          }
#pragma unroll
      for (int o = 0; o < 16; ++o) {
        const int oc = (wid << 4) + o;
        const float* wr = W3 + (oc * 32 + ic) * 27;     // uniform -> s_load
#pragma unroll
        for (int tp = 0; tp < 27; ++tp) acc3[o] = fmaf(wr[tp], xv[tp], acc3[o]);
      }
    }
  }

  // ================= bias+relu, mean-pool over 64 spatials, FC =================
#pragma unroll
  for (int o = 0; o < 16; ++o) {
    float r = fmaxf(acc3[o] + b3[(wid << 4) + o], 0.f);
    r += __shfl_xor(r, 1);
    r += __shfl_xor(r, 2);
    r += __shfl_xor(r, 4);
    r += __shfl_xor(r, 8);
    r += __shfl_xor(r, 16);
    r += __shfl_xor(r, 32);
    if (l == 0) pooled[(wid << 4) + o] = r * 0.015625f;  // /64
  }
  __syncthreads();
  if (t < 64) {
    float a = bfc[t];
#pragma unroll 8
    for (int k = 0; k < 64; ++k) a = fmaf(pooled[k], Wfc[(k << 6) + t], a);
    out[e * 64 + t] = a;
  }
}

// ---------------------------------------------------------------------------
extern "C" void kernel_launch(void* const* d_in, const int* in_sizes, int n_in,
                              void* d_out, int out_size, void* d_ws, size_t ws_size,
                              hipStream_t stream) {
  const float* data = (const float*)d_in[0];
  const int*   clusts = (const int*)d_in[1];
  const unsigned char* maskb = (const unsigned char*)d_in[2];
  const void*  eidx = d_in[3];
  const float* W1 = (const float*)d_in[4];
  const float* b1 = (const float*)d_in[5];
  const float* W2 = (const float*)d_in[6];
  const float* b2 = (const float*)d_in[7];
  const float* W3 = (const float*)d_in[8];
  const float* b3 = (const float*)d_in[9];
  const float* Wfc = (const float*)d_in[10];
  const float* bfc = (const float*)d_in[11];

  const int C = in_sizes[1] / PPC;   // 256
  const int E = in_sizes[3] / 2;     // 1024

  float* y1 = (float*)d_ws;          // C*16*4096 floats = 64 MB

  k_vox_conv1<<<C, 256, 0, stream>>>(data, clusts, maskb, W1, y1);
  k_edge<<<E, 256, 0, stream>>>(eidx, y1, b1, W2, b2, W3, b3, Wfc, bfc,
                                (float*)d_out, E);
}

// Round 5
// 1253.226 us; speedup vs baseline: 1.0893x; 1.0893x over previous
//
#include <hip/hip_runtime.h>

// Problem constants (from setup_inputs): N=32768 pts, C=256 clusters, P=128,
// E=1024 edges, grid 32^3. Channels 1->16->32->64, three stride-2 SAME convs.
#define PPC 128

// Fractional box-overlap of [v, v+gs] with cell [i/32, (i+1)/32], divided by gs.
__device__ __forceinline__ float ovlap(float v, float gs, float inv_gs, int i) {
  const float ns = 0.03125f;                 // 1/32, exact
  float lo = (float)i * ns;                  // exact (multiple of 2^-5)
  float o  = fminf(v + gs, lo + ns) - fmaxf(v, lo);
  return fmaxf(o, 0.0f) * inv_gs;
}

// ---------------------------------------------------------------------------
// Kernel 1: per-cluster voxelize (in LDS) + conv1 (preact, no bias/relu)
//   y1[c][oc(16)][z16][y16][x16]  (fp32, 64 MB in d_ws)
// One block (256 thr) per cluster. LDS: 128KB vox + 3KB reduce.
// ---------------------------------------------------------------------------
__global__ __launch_bounds__(256) void k_vox_conv1(
    const float* __restrict__ data,           // [32768,5]
    const int*   __restrict__ clusts,         // [C,128]
    const unsigned char* __restrict__ maskb,  // [C,128] bool bytes (or int32 - detected)
    const float* __restrict__ W1,             // [16,27]
    float* __restrict__ y1)                   // [C,16,4096]
{
  __shared__ float vox[32768];
  __shared__ float rmn[PPC * 3];
  __shared__ float rmx[PPC * 3];
  const int c = blockIdx.x;
  const int t = threadIdx.x;

  for (int i = t; i < 32768; i += 256) vox[i] = 0.f;

  // mask dtype sniff: all-true mask => bool bytes give maskb[1]==1, int32 gives 0
  const bool m32 = (maskb[1] == 0);

  if (t < PPC) {
    int idx = clusts[c * PPC + t];
    const float* dp = data + idx * 5;
    bool m = m32 ? (((const int*)maskb)[c * PPC + t] != 0)
                 : (maskb[c * PPC + t] != 0);
#pragma unroll
    for (int d = 0; d < 3; ++d) {
      float p = dp[d];
      rmn[t * 3 + d] = m ? p : 1e9f;
      rmx[t * 3 + d] = m ? p : -1e9f;
    }
  }
  __syncthreads();
  for (int off = 64; off >= 1; off >>= 1) {
    if (t < off) {
#pragma unroll
      for (int d = 0; d < 3; ++d) {
        rmn[t * 3 + d] = fminf(rmn[t * 3 + d], rmn[(t + off) * 3 + d]);
        rmx[t * 3 + d] = fmaxf(rmx[t * 3 + d], rmx[(t + off) * 3 + d]);
      }
    }
    __syncthreads();
  }
  const float mn0 = rmn[0], mn1 = rmn[1], mn2 = rmn[2];
  const float rg0 = rmx[0] - mn0, rg1 = rmx[1] - mn1, rg2 = rmx[2] - mn2;
  const float mr = fmaxf(rg0, fmaxf(rg1, rg2)) + 1.0f;
  const float gs = 1.0f / mr;
  const float inv_gs = 1.0f / gs;

  // ---- scatter: 2 threads per point, split outer-i by parity ----
  {
    const int p = t >> 1, h = t & 1;
    int idx = clusts[c * PPC + p];
    const float* dp = data + idx * 5;
    bool m = m32 ? (((const int*)maskb)[c * PPC + p] != 0)
                 : (maskb[c * PPC + p] != 0);
    float w = m ? dp[4] : 0.f;
    if (w != 0.f) {
      float v0 = (dp[0] - mn0 - rg0 * 0.5f - 0.5f) * gs + 0.5f;
      float v1 = (dp[1] - mn1 - rg1 * 0.5f - 0.5f) * gs + 0.5f;
      float v2 = (dp[2] - mn2 - rg2 * 0.5f - 0.5f) * gs + 0.5f;
      int i0 = max(0, (int)floorf(v0 * 32.f) - 1), i1 = min(31, (int)floorf((v0 + gs) * 32.f) + 1);
      int j0 = max(0, (int)floorf(v1 * 32.f) - 1), j1 = min(31, (int)floorf((v1 + gs) * 32.f) + 1);
      int k0 = max(0, (int)floorf(v2 * 32.f) - 1), k1 = min(31, (int)floorf((v2 + gs) * 32.f) + 1);
      for (int i = i0 + h; i <= i1; i += 2) {
        float oi = ovlap(v0, gs, inv_gs, i);
        if (oi <= 0.f) continue;
        float wi = w * oi;
        for (int j = j0; j <= j1; ++j) {
          float oj = ovlap(v1, gs, inv_gs, j);
          if (oj <= 0.f) continue;
          float wij = wi * oj;
          for (int k = k0; k <= k1; ++k) {
            float ok = ovlap(v2, gs, inv_gs, k);
            if (ok > 0.f) atomicAdd(&vox[(i << 10) + (j << 5) + k], wij * ok);
          }
        }
      }
    }
  }
  __syncthreads();

  // ---- conv1: 16 spatials/thread, 16 oc each. SAME pad: in = 2o+t, pad at 32 ----
  for (int si = 0; si < 16; ++si) {
    int s = t + (si << 8);                    // 0..4095, z = s>>8 (= si), y, x
    int oz = s >> 8, oy = (s >> 4) & 15, ox = s & 15;
    float xv[27];
#pragma unroll
    for (int td = 0; td < 3; ++td)
#pragma unroll
      for (int th = 0; th < 3; ++th)
#pragma unroll
        for (int tw = 0; tw < 3; ++tw) {
          int z = 2 * oz + td, y = 2 * oy + th, x = 2 * ox + tw;
          bool okb = (z < 32) & (y < 32) & (x < 32);
          xv[(td * 3 + th) * 3 + tw] = okb ? vox[(z << 10) + (y << 5) + x] : 0.f;
        }
#pragma unroll
    for (int oc = 0; oc < 16; ++oc) {
      float a = 0.f;
#pragma unroll
      for (int tp = 0; tp < 27; ++tp) a = fmaf(W1[oc * 27 + tp], xv[tp], a);
      y1[(((c << 4) + oc) << 12) + s] = a;    // preact: bias+relu applied in k_edge
    }
  }
}

// ---------------------------------------------------------------------------
// Kernel 2: per-edge fused conv2+conv3+pool+FC. One block (256 thr) per edge.
// x1 = relu(y1[ca]+y1[cb]+b1) staged 2ch at a time into LDS [2][17][17][17];
// conv2 accumulates 2 spatial x 32oc in regs; x2 -> LDS (padded z*85+y*10+x)
// in two 16-ch halves; conv3 16oc/wave; shfl pool; fused FC.
//
// R2 fix: the `half` loop is now FULLY UNROLLED. With `#pragma unroll 1` the
// index oc=(half<<4)+o into acc2 was runtime -> entire acc2 array allocated
// in scratch (rule #20): VGPR_Count=68, WRITE_SIZE=993MB/dispatch, 1310us.
// All acc2 indices must be compile-time constants.
// ---------------------------------------------------------------------------
__global__ __launch_bounds__(256) void k_edge(
    const void*  __restrict__ eidx_raw,       // [2,E] int32 or int64 (detected)
    const float* __restrict__ y1,             // [C,16,4096]
    const float* __restrict__ b1,             // 16
    const float* __restrict__ W2,             // [32,16,27]
    const float* __restrict__ b2,             // 32
    const float* __restrict__ W3,             // [64,32,27]
    const float* __restrict__ b3,             // 64
    const float* __restrict__ Wfc,            // [64,64] (k-major)
    const float* __restrict__ bfc,            // 64
    float* __restrict__ out,                  // [E,64]
    int E)
{
  constexpr int ICS = 688;                    // padded x2 ch-stride (z*85+y*10+x, max 672)
  __shared__ float smem[16 * ICS];            // 43KB; also holds x1 stage (2*4913=9826)
  __shared__ float pooled[64];
  const int e = blockIdx.x;
  const int t = threadIdx.x;

  // edge_index dtype sniff (values < 256 -> int64 high words are 0)
  const int* e32 = (const int*)eidx_raw;
  const long long* e64 = (const long long*)eidx_raw;
  const bool is64 = (e32[1] == 0) & (e32[3] == 0) & (e32[5] == 0) & (e32[7] == 0);
  const int ca = is64 ? (int)e64[e] : e32[e];
  const int cb = is64 ? (int)e64[E + e] : e32[E + e];
  const float* Ap = y1 + (size_t)ca * 65536;
  const float* Bp = y1 + (size_t)cb * 65536;

  float acc2[2][32];
#pragma unroll
  for (int h = 0; h < 2; ++h)
#pragma unroll
    for (int o = 0; o < 32; ++o) acc2[h][o] = 0.f;

  const int oz0 = t >> 6, oy0 = (t >> 3) & 7, ox0 = t & 7;  // spatial s0=t, s1=t+256

  // ================= conv2 =================
  for (int icg = 0; icg < 8; ++icg) {
    __syncthreads();
    // stage 2 input channels: [icl][z17][y17][x17], coord 16 = SAME right-pad (zero)
#pragma unroll 4
    for (int i = t; i < 9826; i += 256) {
      int icl = i / 4913;
      int r = i - icl * 4913;
      int z = r / 289; r -= z * 289;
      int y = r / 17;
      int x = r - y * 17;
      float vv = 0.f;
      if ((z < 16) & (y < 16) & (x < 16)) {
        int ic = icg * 2 + icl;
        int gg = (ic << 12) + (z << 8) + (y << 4) + x;
        vv = fmaxf(Ap[gg] + Bp[gg] + b1[ic], 0.f);
      }
      smem[i] = vv;
    }
    __syncthreads();
#pragma unroll 1
    for (int icl = 0; icl < 2; ++icl) {
      const int ic = icg * 2 + icl;
      float xv0[27], xv1[27];
#pragma unroll
      for (int td = 0; td < 3; ++td)
#pragma unroll
        for (int th = 0; th < 3; ++th)
#pragma unroll
          for (int tw = 0; tw < 3; ++tw) {
            int zz = 2 * oz0 + td, yy = 2 * oy0 + th, xx = 2 * ox0 + tw;
            int base = icl * 4913 + zz * 289 + yy * 17 + xx;
            int tp = (td * 3 + th) * 3 + tw;
            xv0[tp] = smem[base];
            xv1[tp] = smem[base + 8 * 289];   // s1 = s0 + 4 in oz -> +8 in z
          }
      const float* wrow = W2 + ic * 27;       // + oc*432
#pragma unroll
      for (int oc = 0; oc < 32; ++oc) {
#pragma unroll
        for (int tp = 0; tp < 27; ++tp) {
          float w = wrow[oc * 432 + tp];      // uniform -> s_load
          acc2[0][oc] = fmaf(w, xv0[tp], acc2[0][oc]);
          acc2[1][oc] = fmaf(w, xv1[tp], acc2[1][oc]);
        }
      }
    }
  }

  // ================= conv3 (two 16-ch halves of x2) =================
  float acc3[16];
#pragma unroll
  for (int o = 0; o < 16; ++o) acc3[o] = 0.f;
  const int l = t & 63, wid = t >> 6;
  const int OZ = l >> 4, OY = (l >> 2) & 3, OX = l & 3;

#pragma unroll            // R2 FIX: must be fully unrolled -> acc2 indices static
  for (int half = 0; half < 2; ++half) {
    __syncthreads();
#pragma unroll
    for (int h = 0; h < 2; ++h) {
      int z = oz0 + (h << 2);
#pragma unroll
      for (int o = 0; o < 16; ++o) {
        int oc = (half << 4) + o;             // compile-time now
        smem[o * ICS + z * 85 + oy0 * 10 + ox0] = fmaxf(acc2[h][oc] + b2[oc], 0.f);
      }
    }
    __syncthreads();
#pragma unroll 1
    for (int icl = 0; icl < 16; ++icl) {
      const int ic = (half << 4) + icl;
      float xv[27];
#pragma unroll
      for (int td = 0; td < 3; ++td)
#pragma unroll
        for (int th = 0; th < 3; ++th)
#pragma unroll
          for (int tw = 0; tw < 3; ++tw) {
            int zz = 2 * OZ + td, yy = 2 * OY + th, xx = 2 * OX + tw;
            bool okb = (zz < 8) & (yy < 8) & (xx < 8);  // coord 8 = SAME right-pad
            xv[(td * 3 + th) * 3 + tw] = okb ? smem[icl * ICS + zz * 85 + yy * 10 + xx] : 0.f;
          }
#pragma unroll
      for (int o = 0; o < 16; ++o) {
        const int oc = (wid << 4) + o;
        const float* wr = W3 + (oc * 32 + ic) * 27;     // uniform -> s_load
#pragma unroll
        for (int tp = 0; tp < 27; ++tp) acc3[o] = fmaf(wr[tp], xv[tp], acc3[o]);
      }
    }
  }

  // ================= bias+relu, mean-pool over 64 spatials, FC =================
#pragma unroll
  for (int o = 0; o < 16; ++o) {
    float r = fmaxf(acc3[o] + b3[(wid << 4) + o], 0.f);
    r += __shfl_xor(r, 1);
    r += __shfl_xor(r, 2);
    r += __shfl_xor(r, 4);
    r += __shfl_xor(r, 8);
    r += __shfl_xor(r, 16);
    r += __shfl_xor(r, 32);
    if (l == 0) pooled[(wid << 4) + o] = r * 0.015625f;  // /64
  }
  __syncthreads();
  if (t < 64) {
    float a = bfc[t];
#pragma unroll 8
    for (int k = 0; k < 64; ++k) a = fmaf(pooled[k], Wfc[(k << 6) + t], a);
    out[e * 64 + t] = a;
  }
}

// ---------------------------------------------------------------------------
extern "C" void kernel_launch(void* const* d_in, const int* in_sizes, int n_in,
                              void* d_out, int out_size, void* d_ws, size_t ws_size,
                              hipStream_t stream) {
  const float* data = (const float*)d_in[0];
  const int*   clusts = (const int*)d_in[1];
  const unsigned char* maskb = (const unsigned char*)d_in[2];
  const void*  eidx = d_in[3];
  const float* W1 = (const float*)d_in[4];
  const float* b1 = (const float*)d_in[5];
  const float* W2 = (const float*)d_in[6];
  const float* b2 = (const float*)d_in[7];
  const float* W3 = (const float*)d_in[8];
  const float* b3 = (const float*)d_in[9];
  const float* Wfc = (const float*)d_in[10];
  const float* bfc = (const float*)d_in[11];

  const int C = in_sizes[1] / PPC;   // 256
  const int E = in_sizes[3] / 2;     // 1024

  float* y1 = (float*)d_ws;          // C*16*4096 floats = 64 MB

  k_vox_conv1<<<C, 256, 0, stream>>>(data, clusts, maskb, W1, y1);
  k_edge<<<E, 256, 0, stream>>>(eidx, y1, b1, W2, b2, W3, b3, Wfc, bfc,
                                (float*)d_out, E);
}

// Round 7
// 893.255 us; speedup vs baseline: 1.5282x; 1.4030x over previous
//
#include <hip/hip_runtime.h>

// Problem constants: N=32768 pts, C=256 clusters, P=128, E=1024 edges,
// grid 32^3. Channels 1->16->32->64, three stride-2 SAME convs.
#define PPC 128

// Fractional box-overlap of [v, v+gs] with cell [i/32, (i+1)/32], divided by gs.
__device__ __forceinline__ float ovlap(float v, float gs, float inv_gs, int i) {
  const float ns = 0.03125f;                 // 1/32, exact
  float lo = (float)i * ns;                  // exact (multiple of 2^-5)
  float o  = fminf(v + gs, lo + ns) - fmaxf(v, lo);
  return fmaxf(o, 0.0f) * inv_gs;
}

// ---------------------------------------------------------------------------
// Kernel 1: per-cluster voxelize (in LDS) + conv1 (preact, no bias/relu)
//   y1[c][oc(16)][z16][y16][x16]  (fp32, 64 MB in d_ws)   (unchanged R5)
// ---------------------------------------------------------------------------
__global__ __launch_bounds__(256) void k_vox_conv1(
    const float* __restrict__ data,           // [32768,5]
    const int*   __restrict__ clusts,         // [C,128]
    const unsigned char* __restrict__ maskb,  // [C,128] bool bytes (or int32 - detected)
    const float* __restrict__ W1,             // [16,27]
    float* __restrict__ y1)                   // [C,16,4096]
{
  __shared__ float vox[32768];
  __shared__ float rmn[PPC * 3];
  __shared__ float rmx[PPC * 3];
  const int c = blockIdx.x;
  const int t = threadIdx.x;

  for (int i = t; i < 32768; i += 256) vox[i] = 0.f;

  const bool m32 = (maskb[1] == 0);   // mask dtype sniff (all-true mask)

  if (t < PPC) {
    int idx = clusts[c * PPC + t];
    const float* dp = data + idx * 5;
    bool m = m32 ? (((const int*)maskb)[c * PPC + t] != 0)
                 : (maskb[c * PPC + t] != 0);
#pragma unroll
    for (int d = 0; d < 3; ++d) {
      float p = dp[d];
      rmn[t * 3 + d] = m ? p : 1e9f;
      rmx[t * 3 + d] = m ? p : -1e9f;
    }
  }
  __syncthreads();
  for (int off = 64; off >= 1; off >>= 1) {
    if (t < off) {
#pragma unroll
      for (int d = 0; d < 3; ++d) {
        rmn[t * 3 + d] = fminf(rmn[t * 3 + d], rmn[(t + off) * 3 + d]);
        rmx[t * 3 + d] = fmaxf(rmx[t * 3 + d], rmx[(t + off) * 3 + d]);
      }
    }
    __syncthreads();
  }
  const float mn0 = rmn[0], mn1 = rmn[1], mn2 = rmn[2];
  const float rg0 = rmx[0] - mn0, rg1 = rmx[1] - mn1, rg2 = rmx[2] - mn2;
  const float mr = fmaxf(rg0, fmaxf(rg1, rg2)) + 1.0f;
  const float gs = 1.0f / mr;
  const float inv_gs = 1.0f / gs;

  {  // scatter: 2 threads per point, split outer-i by parity
    const int p = t >> 1, h = t & 1;
    int idx = clusts[c * PPC + p];
    const float* dp = data + idx * 5;
    bool m = m32 ? (((const int*)maskb)[c * PPC + p] != 0)
                 : (maskb[c * PPC + p] != 0);
    float w = m ? dp[4] : 0.f;
    if (w != 0.f) {
      float v0 = (dp[0] - mn0 - rg0 * 0.5f - 0.5f) * gs + 0.5f;
      float v1 = (dp[1] - mn1 - rg1 * 0.5f - 0.5f) * gs + 0.5f;
      float v2 = (dp[2] - mn2 - rg2 * 0.5f - 0.5f) * gs + 0.5f;
      int i0 = max(0, (int)floorf(v0 * 32.f) - 1), i1 = min(31, (int)floorf((v0 + gs) * 32.f) + 1);
      int j0 = max(0, (int)floorf(v1 * 32.f) - 1), j1 = min(31, (int)floorf((v1 + gs) * 32.f) + 1);
      int k0 = max(0, (int)floorf(v2 * 32.f) - 1), k1 = min(31, (int)floorf((v2 + gs) * 32.f) + 1);
      for (int i = i0 + h; i <= i1; i += 2) {
        float oi = ovlap(v0, gs, inv_gs, i);
        if (oi <= 0.f) continue;
        float wi = w * oi;
        for (int j = j0; j <= j1; ++j) {
          float oj = ovlap(v1, gs, inv_gs, j);
          if (oj <= 0.f) continue;
          float wij = wi * oj;
          for (int k = k0; k <= k1; ++k) {
            float ok = ovlap(v2, gs, inv_gs, k);
            if (ok > 0.f) atomicAdd(&vox[(i << 10) + (j << 5) + k], wij * ok);
          }
        }
      }
    }
  }
  __syncthreads();

  // conv1: 16 spatials/thread, 16 oc each. SAME: in = 2o+t, right-pad at 32.
  for (int si = 0; si < 16; ++si) {
    int s = t + (si << 8);
    int oz = s >> 8, oy = (s >> 4) & 15, ox = s & 15;
    float xv[27];
#pragma unroll
    for (int td = 0; td < 3; ++td)
#pragma unroll
      for (int th = 0; th < 3; ++th)
#pragma unroll
        for (int tw = 0; tw < 3; ++tw) {
          int z = 2 * oz + td, y = 2 * oy + th, x = 2 * ox + tw;
          bool okb = (z < 32) & (y < 32) & (x < 32);
          xv[(td * 3 + th) * 3 + tw] = okb ? vox[(z << 10) + (y << 5) + x] : 0.f;
        }
#pragma unroll
    for (int oc = 0; oc < 16; ++oc) {
      float a = 0.f;
#pragma unroll
      for (int tp = 0; tp < 27; ++tp) a = fmaf(W1[oc * 27 + tp], xv[tp], a);
      y1[(((c << 4) + oc) << 12) + s] = a;
    }
  }
}

// ---------------------------------------------------------------------------
// Kernel 2 (R5 restructure): per-edge fused conv2+conv3+pool+FC.
//  - conv2 staging: 1 ch, double-buffered [2][17^3]; thread=(y,x) identity
//    mapping -> no divides, no predicates, coalesced; 1 barrier/round.
//  - conv3: x2 in oc-QUARTERS, padded [8ch][9][9][9] -> no read predicates,
//    23.3KB max. LDS total 39.6KB -> 4 blocks/CU (was 44.5KB -> 3).
//  - __launch_bounds__(256,4): VGPR<=128 so occupancy is LDS-limited only.
//  (R2 lesson kept: ALL register-array indices compile-time.)
// ---------------------------------------------------------------------------
#define S1 4913                // 17*17*17 one-channel staging volume
__global__ __launch_bounds__(256, 4) void k_edge(
    const void*  __restrict__ eidx_raw,       // [2,E] int32 or int64 (detected)
    const float* __restrict__ y1,             // [C,16,4096]
    const float* __restrict__ b1,             // 16
    const float* __restrict__ W2,             // [32,16,27]
    const float* __restrict__ b2,             // 32
    const float* __restrict__ W3,             // [64,32,27]
    const float* __restrict__ b3,             // 64
    const float* __restrict__ Wfc,            // [64,64] (k-major)
    const float* __restrict__ bfc,            // 64
    float* __restrict__ out,                  // [E,64]
    int E)
{
  __shared__ float smem[2 * S1 + 64];         // 9826 stage / 5832 x2q (aliased) + pooled
  float* pooled = smem + 2 * S1;
  const int e = blockIdx.x;
  const int t = threadIdx.x;

  // edge_index dtype sniff (values < 256 -> int64 high words are 0)
  const int* e32 = (const int*)eidx_raw;
  const long long* e64 = (const long long*)eidx_raw;
  const bool is64 = (e32[1] == 0) & (e32[3] == 0) & (e32[5] == 0) & (e32[7] == 0);
  const int ca = is64 ? (int)e64[e] : e32[e];
  const int cb = is64 ? (int)e64[E + e] : e32[E + e];
  const float* Ap = y1 + (size_t)ca * 65536;
  const float* Bp = y1 + (size_t)cb * 65536;

  float acc2[2][32];
#pragma unroll
  for (int h = 0; h < 2; ++h)
#pragma unroll
    for (int o = 0; o < 32; ++o) acc2[h][o] = 0.f;

  const int oz0 = t >> 6, oy0 = (t >> 3) & 7, ox0 = t & 7;  // conv2 spatial: s0=t, s1=t+256
  const int stw = (t >> 4) * 17 + (t & 15);                 // staging (y,x) -> 17-stride slot

  // zero both stage buffers once (covers all pad cells; interior overwritten)
  for (int i = t; i < 2 * S1; i += 256) smem[i] = 0.f;

  // ---- prologue: stage ch 0 into buf 0 ----
  {
    const float* Aic = Ap;  const float* Bic = Bp;
    const float bb = b1[0];
#pragma unroll 4
    for (int z = 0; z < 16; ++z)
      smem[stw + z * 289] = fmaxf(Aic[(z << 8) + t] + Bic[(z << 8) + t] + bb, 0.f);
  }
  __syncthreads();

  // ================= conv2: 16 rounds, double-buffered =================
#pragma unroll 2
  for (int ic = 0; ic < 16; ++ic) {
    // stage next channel into the other buffer (issues loads early; latency
    // hides under this round's FMAs)
    if (ic < 15) {
      const int icn = ic + 1;
      const float* Aic = Ap + (icn << 12);
      const float* Bic = Bp + (icn << 12);
      const float bb = b1[icn];
      const int wb = (icn & 1) * S1 + stw;
#pragma unroll 4
      for (int z = 0; z < 16; ++z)
        smem[wb + z * 289] = fmaxf(Aic[(z << 8) + t] + Bic[(z << 8) + t] + bb, 0.f);
    }
    // compute this channel from its buffer
    {
      const int rb = (ic & 1) * S1 + oz0 * 578 + oy0 * 34 + 2 * ox0;  // zz=2oz0,yy=2oy0,xx=2ox0
      float xv0[27], xv1[27];
#pragma unroll
      for (int td = 0; td < 3; ++td)
#pragma unroll
        for (int th = 0; th < 3; ++th)
#pragma unroll
          for (int tw = 0; tw < 3; ++tw) {
            const int off = td * 289 + th * 17 + tw;
            const int tp = (td * 3 + th) * 3 + tw;
            xv0[tp] = smem[rb + off];
            xv1[tp] = smem[rb + 2312 + off];   // s1: +8 in z = +8*289
          }
      const float* wrow = W2 + ic * 27;        // + oc*432 (uniform -> s_load)
#pragma unroll
      for (int oc = 0; oc < 32; ++oc) {
#pragma unroll
        for (int tp = 0; tp < 27; ++tp) {
          const float w = wrow[oc * 432 + tp];
          acc2[0][oc] = fmaf(w, xv0[tp], acc2[0][oc]);
          acc2[1][oc] = fmaf(w, xv1[tp], acc2[1][oc]);
        }
      }
    }
    __syncthreads();   // one barrier/round: next round reuses the buffer we just read
  }

  // ================= conv3: 4 oc-quarters of x2, padded [8][9][9][9] =======
  float acc3[16];
#pragma unroll
  for (int o = 0; o < 16; ++o) acc3[o] = 0.f;
  const int l = t & 63, wid = t >> 6;
  const int OZ = l >> 4, OY = (l >> 2) & 3, OX = l & 3;     // conv3 spatial 4^3
  const int rb3 = OZ * 162 + OY * 18 + 2 * OX;              // zz=2OZ etc (81/9 strides)

#pragma unroll
  for (int q = 0; q < 4; ++q) {
    // zero whole quarter buffer (re-establishes pads; region reused by staging)
    for (int i = t; i < 5832; i += 256) smem[i] = 0.f;
    __syncthreads();
#pragma unroll
    for (int h = 0; h < 2; ++h)
#pragma unroll
      for (int o = 0; o < 8; ++o) {
        const int oc = (q << 3) + o;           // compile-time (q,o unrolled)
        smem[o * 729 + (oz0 + (h << 2)) * 81 + oy0 * 9 + ox0] =
            fmaxf(acc2[h][oc] + b2[oc], 0.f);
      }
    __syncthreads();
#pragma unroll 1
    for (int icl = 0; icl < 8; ++icl) {
      const int ic3 = (q << 3) + icl;
      float xv[27];
#pragma unroll
      for (int td = 0; td < 3; ++td)
#pragma unroll
        for (int th = 0; th < 3; ++th)
#pragma unroll
          for (int tw = 0; tw < 3; ++tw)
            xv[(td * 3 + th) * 3 + tw] =
                smem[icl * 729 + rb3 + td * 81 + th * 9 + tw];  // pads = 0, no predicates
#pragma unroll
      for (int o = 0; o < 16; ++o) {
        const int oc = (wid << 4) + o;
        const float* wr = W3 + (oc * 32 + ic3) * 27;   // uniform -> s_load
#pragma unroll
        for (int tp = 0; tp < 27; ++tp) acc3[o] = fmaf(wr[tp], xv[tp], acc3[o]);
      }
    }
    __syncthreads();
  }

  // ================= bias+relu, mean-pool over 64 spatials, FC =============
#pragma unroll
  for (int o = 0; o < 16; ++o) {
    float r = fmaxf(acc3[o] + b3[(wid << 4) + o], 0.f);
    r += __shfl_xor(r, 1);
    r += __shfl_xor(r, 2);
    r += __shfl_xor(r, 4);
    r += __shfl_xor(r, 8);
    r += __shfl_xor(r, 16);
    r += __shfl_xor(r, 32);
    if (l == 0) pooled[(wid << 4) + o] = r * 0.015625f;  // /64
  }
  __syncthreads();
  if (t < 64) {
    float a = bfc[t];
#pragma unroll 8
    for (int k = 0; k < 64; ++k) a = fmaf(pooled[k], Wfc[(k << 6) + t], a);
    out[e * 64 + t] = a;
  }
}

// ---------------------------------------------------------------------------
extern "C" void kernel_launch(void* const* d_in, const int* in_sizes, int n_in,
                              void* d_out, int out_size, void* d_ws, size_t ws_size,
                              hipStream_t stream) {
  const float* data = (const float*)d_in[0];
  const int*   clusts = (const int*)d_in[1];
  const unsigned char* maskb = (const unsigned char*)d_in[2];
  const void*  eidx = d_in[3];
  const float* W1 = (const float*)d_in[4];
  const float* b1 = (const float*)d_in[5];
  const float* W2 = (const float*)d_in[6];
  const float* b2 = (const float*)d_in[7];
  const float* W3 = (const float*)d_in[8];
  const float* b3 = (const float*)d_in[9];
  const float* Wfc = (const float*)d_in[10];
  const float* bfc = (const float*)d_in[11];

  const int C = in_sizes[1] / PPC;   // 256
  const int E = in_sizes[3] / 2;     // 1024

  float* y1 = (float*)d_ws;          // C*16*4096 floats = 64 MB

  k_vox_conv1<<<C, 256, 0, stream>>>(data, clusts, maskb, W1, y1);
  k_edge<<<E, 256, 0, stream>>>(eidx, y1, b1, W2, b2, W3, b3, Wfc, bfc,
                                (float*)d_out, E);
}